// Round 1
// baseline (35.734 us; speedup 1.0000x reference)
//
#include <hip/hip_runtime.h>
#include <math.h>

#define NBATCH 8
#define PTOT   4096
#define NG     2048          // points per group
#define QB     256           // queries per block (= threads)
#define BLKS_PER_PROB (NG / QB)          // 8
#define NPROB  32                        // 8 batches x 2 groups x 2 directions
#define NBLK   (NPROB * BLKS_PER_PROB)   // 256

// One block: one (batch, group, direction, query-tile). Stage all 2048 ref
// points (as float4: x,y,z,|r|^2) in LDS; each thread owns one query point and
// scans all refs computing min over (|r|^2 - 2 q.r); |q|^2 added after the min.
__global__ __launch_bounds__(256) void chamfer_partial(
    const float* __restrict__ x, const float* __restrict__ y,
    float* __restrict__ partial)
{
    __shared__ float4 ref[NG];     // 32 KiB
    __shared__ float  wsum[4];

    const int blk   = blockIdx.x;
    const int prob  = blk / BLKS_PER_PROB;   // 0..31
    const int qtile = blk % BLKS_PER_PROB;   // 0..7
    const int dir   = prob >> 4;             // 0: x->y, 1: y->x
    const int bg    = prob & 15;
    const int b     = bg >> 1;               // batch
    const int g     = bg & 1;                // group

    const float* qb = (dir == 0 ? x : y) + (size_t)(b * PTOT + g * NG) * 3;
    const float* rb = (dir == 0 ? y : x) + (size_t)(b * PTOT + g * NG) * 3;

    const int tid = threadIdx.x;

    // Stage refs into LDS (SoA-in-float4: x,y,z, |r|^2).
    for (int i = tid; i < NG; i += QB) {
        float rx = rb[i * 3 + 0];
        float ry = rb[i * 3 + 1];
        float rz = rb[i * 3 + 2];
        float rn = fmaf(rx, rx, fmaf(ry, ry, rz * rz));
        ref[i] = make_float4(rx, ry, rz, rn);
    }
    __syncthreads();

    const int q = qtile * QB + tid;
    const float qx = qb[q * 3 + 0];
    const float qy = qb[q * 3 + 1];
    const float qz = qb[q * 3 + 2];
    const float ax = -2.0f * qx, ay = -2.0f * qy, az = -2.0f * qz;
    const float qn = fmaf(qx, qx, fmaf(qy, qy, qz * qz));

    // 4 independent min-chains for ILP; inner body = 3 FMA + 1 min per pair.
    float m0 = 3.4e38f, m1 = 3.4e38f, m2 = 3.4e38f, m3 = 3.4e38f;
    for (int n = 0; n < NG; n += 4) {
        float4 r0 = ref[n + 0];
        float4 r1 = ref[n + 1];
        float4 r2 = ref[n + 2];
        float4 r3 = ref[n + 3];
        float t0 = fmaf(r0.z, az, fmaf(r0.y, ay, fmaf(r0.x, ax, r0.w)));
        float t1 = fmaf(r1.z, az, fmaf(r1.y, ay, fmaf(r1.x, ax, r1.w)));
        float t2 = fmaf(r2.z, az, fmaf(r2.y, ay, fmaf(r2.x, ax, r2.w)));
        float t3 = fmaf(r3.z, az, fmaf(r3.y, ay, fmaf(r3.x, ax, r3.w)));
        m0 = fminf(m0, t0);
        m1 = fminf(m1, t1);
        m2 = fminf(m2, t2);
        m3 = fminf(m3, t3);
    }
    float md2 = fminf(fminf(m0, m1), fminf(m2, m3)) + qn;
    md2 = fmaxf(md2, 0.0f);          // guard tiny negative from cancellation
    float d = sqrtf(md2);

    // Block-reduce sum of nearest distances.
    for (int off = 32; off > 0; off >>= 1)
        d += __shfl_down(d, off, 64);
    if ((tid & 63) == 0) wsum[tid >> 6] = d;
    __syncthreads();
    if (tid == 0)
        partial[blk] = (wsum[0] + wsum[1]) + (wsum[2] + wsum[3]);
}

// Deterministic final reduction of the 256 per-block partials.
__global__ __launch_bounds__(256) void chamfer_reduce(
    const float* __restrict__ partial, float* __restrict__ out)
{
    __shared__ float s[4];
    const int tid = threadIdx.x;
    float v = partial[tid];
    for (int off = 32; off > 0; off >>= 1)
        v += __shfl_down(v, off, 64);
    if ((tid & 63) == 0) s[tid >> 6] = v;
    __syncthreads();
    if (tid == 0)
        out[0] = ((s[0] + s[1]) + (s[2] + s[3])) * (1.0f / 16384.0f);
}

extern "C" void kernel_launch(void* const* d_in, const int* in_sizes, int n_in,
                              void* d_out, int out_size, void* d_ws, size_t ws_size,
                              hipStream_t stream) {
    const float* x = (const float*)d_in[0];
    const float* y = (const float*)d_in[1];
    float* out     = (float*)d_out;
    float* partial = (float*)d_ws;   // 256 floats

    chamfer_partial<<<NBLK, QB, 0, stream>>>(x, y, partial);
    chamfer_reduce<<<1, 256, 0, stream>>>(partial, out);
}

// Round 2
// 21.665 us; speedup vs baseline: 1.6494x; 1.6494x over previous
//
#include <hip/hip_runtime.h>
#include <math.h>

#define NBATCH 8
#define PTOT   4096
#define NG     2048              // points per group
#define S      16                // ref slices per problem
#define SLEN   (NG / S)          // 128 refs per slice
#define QPT    8                 // queries per thread
#define NT     256               // threads per block
#define NPROB  32                // 8 batches x 2 groups x 2 directions
#define NBLK1  (NPROB * S)       // 512 blocks, pass 1
#define NPART  (NPROB * S * NG)  // per-slice per-query partial mins (1M floats)

// Pass 1: one block = (problem, ref-slice). Stage the 128-ref slice in LDS as
// float4 (x,y,z,|r|^2). Each thread owns 8 queries; per ref point one
// broadcast ds_read feeds 8 dot products. Partial min of (|r|^2 - 2 q.r + |q|^2)
// per (query, slice) written to d_ws.
__global__ __launch_bounds__(256) void chamfer_pass1(
    const float* __restrict__ x, const float* __restrict__ y,
    float* __restrict__ pmin)
{
    __shared__ float4 ref[SLEN];   // 2 KiB

    const int blk   = blockIdx.x;
    const int slice = blk % S;
    const int prob  = blk / S;               // 0..31
    const int dir   = prob >> 4;             // 0: x->y, 1: y->x
    const int bg    = prob & 15;
    const int b     = bg >> 1;               // batch
    const int g     = bg & 1;                // group

    const float* qb = (dir == 0 ? x : y) + (size_t)(b * PTOT + g * NG) * 3;
    const float* rb = (dir == 0 ? y : x) + (size_t)(b * PTOT + g * NG) * 3;

    const int tid = threadIdx.x;

    if (tid < SLEN) {
        const int i = slice * SLEN + tid;
        float rx = rb[i * 3 + 0];
        float ry = rb[i * 3 + 1];
        float rz = rb[i * 3 + 2];
        ref[tid] = make_float4(rx, ry, rz, fmaf(rx, rx, fmaf(ry, ry, rz * rz)));
    }
    __syncthreads();

    float ax[QPT], ay[QPT], az[QPT], qn[QPT], mn[QPT];
    #pragma unroll
    for (int k = 0; k < QPT; k++) {
        const int q = k * NT + tid;
        float qx = qb[q * 3 + 0];
        float qy = qb[q * 3 + 1];
        float qz = qb[q * 3 + 2];
        ax[k] = -2.0f * qx; ay[k] = -2.0f * qy; az[k] = -2.0f * qz;
        qn[k] = fmaf(qx, qx, fmaf(qy, qy, qz * qz));
        mn[k] = 3.4e38f;
    }

    // 8 independent min-chains; per 2 refs: 2 broadcast ds_read_b128 + 64 VALU.
    #pragma unroll 4
    for (int n = 0; n < SLEN; n += 2) {
        float4 r0 = ref[n + 0];
        float4 r1 = ref[n + 1];
        #pragma unroll
        for (int k = 0; k < QPT; k++) {
            float t0 = fmaf(r0.z, az[k], fmaf(r0.y, ay[k], fmaf(r0.x, ax[k], r0.w)));
            float t1 = fmaf(r1.z, az[k], fmaf(r1.y, ay[k], fmaf(r1.x, ax[k], r1.w)));
            mn[k] = fminf(mn[k], t0);
            mn[k] = fminf(mn[k], t1);
        }
    }

    #pragma unroll
    for (int k = 0; k < QPT; k++)
        pmin[(size_t)(prob * S + slice) * NG + k * NT + tid] = mn[k] + qn[k];
}

// Pass 2: per (problem, query) min over the 16 slices, sqrt, block-sum.
__global__ __launch_bounds__(256) void chamfer_pass2(
    const float* __restrict__ pmin, float* __restrict__ bsum)
{
    __shared__ float s4[4];
    const int gid  = blockIdx.x * 256 + threadIdx.x;   // 0..65535
    const int prob = gid >> 11;                        // /2048
    const int q    = gid & (NG - 1);

    float m = 3.4e38f;
    #pragma unroll
    for (int s = 0; s < S; s++)
        m = fminf(m, pmin[(size_t)(prob * S + s) * NG + q]);

    float d = sqrtf(fmaxf(m, 0.0f));   // guard cancellation

    for (int off = 32; off > 0; off >>= 1)
        d += __shfl_down(d, off, 64);
    if ((threadIdx.x & 63) == 0) s4[threadIdx.x >> 6] = d;
    __syncthreads();
    if (threadIdx.x == 0)
        bsum[blockIdx.x] = (s4[0] + s4[1]) + (s4[2] + s4[3]);
}

// Pass 3: deterministic reduction of the 256 block sums.
__global__ __launch_bounds__(256) void chamfer_pass3(
    const float* __restrict__ bsum, float* __restrict__ out)
{
    __shared__ float s4[4];
    const int tid = threadIdx.x;
    float v = bsum[tid];
    for (int off = 32; off > 0; off >>= 1)
        v += __shfl_down(v, off, 64);
    if ((tid & 63) == 0) s4[tid >> 6] = v;
    __syncthreads();
    if (tid == 0)
        out[0] = ((s4[0] + s4[1]) + (s4[2] + s4[3])) * (1.0f / 16384.0f);
}

extern "C" void kernel_launch(void* const* d_in, const int* in_sizes, int n_in,
                              void* d_out, int out_size, void* d_ws, size_t ws_size,
                              hipStream_t stream) {
    const float* x = (const float*)d_in[0];
    const float* y = (const float*)d_in[1];
    float* out  = (float*)d_out;
    float* pmin = (float*)d_ws;                 // 1M floats (4 MB)
    float* bsum = pmin + NPART;                 // 256 floats

    chamfer_pass1<<<NBLK1, NT, 0, stream>>>(x, y, pmin);
    chamfer_pass2<<<256, 256, 0, stream>>>(pmin, bsum);
    chamfer_pass3<<<1, 256, 0, stream>>>(bsum, out);
}

// Round 3
// 21.345 us; speedup vs baseline: 1.6741x; 1.0150x over previous
//
#include <hip/hip_runtime.h>
#include <math.h>

#define NBATCH 8
#define PTOT   4096
#define NG     2048              // points per group
#define S      16                // ref slices per problem
#define SLEN   (NG / S)          // 128 refs per slice
#define QPT    8                 // queries per thread (consecutive)
#define NT     256               // threads per block
#define NPROB  32                // 8 batches x 2 groups x 2 directions
#define NBLK1  (NPROB * S)       // 512 blocks, pass 1
#define NPART  (NPROB * S * NG)  // per-slice per-query partial mins (1M floats)

// Pass 1: one block = (problem, ref-slice). Each thread owns 8 CONSECUTIVE
// queries (96B contiguous -> 6 float4 loads, hoisted above the barrier).
// Ref slice staged via 96 float4 global loads -> LDS raw -> AoS (x,y,z,|r|^2).
// Inner: per ref point one broadcast ds_read_b128 feeds 8 dot products;
// min merged via fminf(fminf(t0,t1),mn) -> v_min3_f32.
__global__ __launch_bounds__(256) void chamfer_pass1(
    const float* __restrict__ x, const float* __restrict__ y,
    float* __restrict__ pmin)
{
    __shared__ float  raw[SLEN * 3];   // 1.5 KiB
    __shared__ float4 ref[SLEN];       // 2 KiB

    const int blk   = blockIdx.x;
    const int slice = blk & (S - 1);
    const int prob  = blk >> 4;              // 0..31
    const int dir   = prob >> 4;             // 0: x->y, 1: y->x
    const int bg    = prob & 15;
    const int b     = bg >> 1;               // batch
    const int g     = bg & 1;                // group

    const float* qb = (dir == 0 ? x : y) + (size_t)(b * PTOT + g * NG) * 3;
    const float* rb = (dir == 0 ? y : x) + (size_t)(b * PTOT + g * NG) * 3;

    const int tid = threadIdx.x;

    // Stage ref slice: 384 floats = 96 float4 (16B-aligned: slice*SLEN*3*4 = 1536B mult).
    if (tid < (SLEN * 3) / 4) {
        float4 v = ((const float4*)(rb + slice * SLEN * 3))[tid];
        ((float4*)raw)[tid] = v;
    }

    // Query loads (independent of staging -> overlap latency with barrier).
    float4 qv[6];
    {
        const float4* qp = (const float4*)(qb + (size_t)tid * QPT * 3);
        #pragma unroll
        for (int i = 0; i < 6; i++) qv[i] = qp[i];
    }

    __syncthreads();

    // Build AoS ref (x,y,z,|r|^2) from raw.
    if (tid < SLEN) {
        float rx = raw[tid * 3 + 0];
        float ry = raw[tid * 3 + 1];
        float rz = raw[tid * 3 + 2];
        ref[tid] = make_float4(rx, ry, rz, fmaf(rx, rx, fmaf(ry, ry, rz * rz)));
    }

    // Unpack queries while LDS settles.
    float ax[QPT], ay[QPT], az[QPT], qn[QPT], mn[QPT];
    const float* qf = reinterpret_cast<const float*>(qv);
    #pragma unroll
    for (int k = 0; k < QPT; k++) {
        float qx = qf[k * 3 + 0];
        float qy = qf[k * 3 + 1];
        float qz = qf[k * 3 + 2];
        ax[k] = -2.0f * qx; ay[k] = -2.0f * qy; az[k] = -2.0f * qz;
        qn[k] = fmaf(qx, qx, fmaf(qy, qy, qz * qz));
        mn[k] = 3.4e38f;
    }

    __syncthreads();

    // 8 independent chains; per 4 refs x 8 queries: 96 FMA + 16 min3.
    #pragma unroll 2
    for (int n = 0; n < SLEN; n += 4) {
        float4 r0 = ref[n + 0];
        float4 r1 = ref[n + 1];
        float4 r2 = ref[n + 2];
        float4 r3 = ref[n + 3];
        #pragma unroll
        for (int k = 0; k < QPT; k++) {
            float t0 = fmaf(r0.z, az[k], fmaf(r0.y, ay[k], fmaf(r0.x, ax[k], r0.w)));
            float t1 = fmaf(r1.z, az[k], fmaf(r1.y, ay[k], fmaf(r1.x, ax[k], r1.w)));
            float t2 = fmaf(r2.z, az[k], fmaf(r2.y, ay[k], fmaf(r2.x, ax[k], r2.w)));
            float t3 = fmaf(r3.z, az[k], fmaf(r3.y, ay[k], fmaf(r3.x, ax[k], r3.w)));
            mn[k] = fminf(fminf(t0, t1), mn[k]);   // -> v_min3_f32
            mn[k] = fminf(fminf(t2, t3), mn[k]);   // -> v_min3_f32
        }
    }

    // 8 contiguous floats per thread -> 2x global_store_dwordx4.
    float* op = pmin + (size_t)(prob * S + slice) * NG + tid * QPT;
    #pragma unroll
    for (int k = 0; k < QPT; k++)
        op[k] = mn[k] + qn[k];
}

// Pass 2: per (problem, query) min over the 16 slices, sqrt, block-sum.
__global__ __launch_bounds__(256) void chamfer_pass2(
    const float* __restrict__ pmin, float* __restrict__ bsum)
{
    __shared__ float s4[4];
    const int gid  = blockIdx.x * 256 + threadIdx.x;   // 0..65535
    const int prob = gid >> 11;                        // /2048
    const int q    = gid & (NG - 1);

    float m = 3.4e38f;
    #pragma unroll
    for (int s = 0; s < S; s++)
        m = fminf(m, pmin[(size_t)(prob * S + s) * NG + q]);

    float d = sqrtf(fmaxf(m, 0.0f));   // guard cancellation

    for (int off = 32; off > 0; off >>= 1)
        d += __shfl_down(d, off, 64);
    if ((threadIdx.x & 63) == 0) s4[threadIdx.x >> 6] = d;
    __syncthreads();
    if (threadIdx.x == 0)
        bsum[blockIdx.x] = (s4[0] + s4[1]) + (s4[2] + s4[3]);
}

// Pass 3: deterministic reduction of the 256 block sums.
__global__ __launch_bounds__(256) void chamfer_pass3(
    const float* __restrict__ bsum, float* __restrict__ out)
{
    __shared__ float s4[4];
    const int tid = threadIdx.x;
    float v = bsum[tid];
    for (int off = 32; off > 0; off >>= 1)
        v += __shfl_down(v, off, 64);
    if ((tid & 63) == 0) s4[tid >> 6] = v;
    __syncthreads();
    if (tid == 0)
        out[0] = ((s4[0] + s4[1]) + (s4[2] + s4[3])) * (1.0f / 16384.0f);
}

extern "C" void kernel_launch(void* const* d_in, const int* in_sizes, int n_in,
                              void* d_out, int out_size, void* d_ws, size_t ws_size,
                              hipStream_t stream) {
    const float* x = (const float*)d_in[0];
    const float* y = (const float*)d_in[1];
    float* out  = (float*)d_out;
    float* pmin = (float*)d_ws;                 // 1M floats (4 MB)
    float* bsum = pmin + NPART;                 // 256 floats

    chamfer_pass1<<<NBLK1, NT, 0, stream>>>(x, y, pmin);
    chamfer_pass2<<<256, 256, 0, stream>>>(pmin, bsum);
    chamfer_pass3<<<1, 256, 0, stream>>>(bsum, out);
}